// Round 12
// baseline (226.489 us; speedup 1.0000x reference)
//
#include <hip/hip_runtime.h>

// VectorQuantizer: x (64,32,32,128) f32, embeddings (128,1024) f32.
// out = x + (q - x), q = e.T[argmin_k ||x_row - e_k||^2]
//
// Cascade (each stage only needs enough precision to RANK):
//   phase 1 (hi-bf16 MFMA, swapped operands A=codes/B=x-rows): per-row argmin
//     in-lane over packed keys (m = dot - nrm/2, 7-bit local code id in mantissa
//     LSBs); -nrm/2 folded in via 9th MFMA. Grid = 256 rowgroups x 8 eighths;
//     2 rowtiles per wave (interleaved MFMA chains). Top-2 tracked with
//     v_med3_f32 (b2' = med3(b1,b2,key)) -> 3 VALU/key.
//   merge: 8 eighths/row, pb layout [row][8] (uint4/float4 loads);
//     s-gap < MARGIN1=0.30 -> wl (~4% rows).
//   rescan: EXACT f64 re-argmin, 8 rows/block share one coalesced e-sweep.
// 5 dispatches (wlc cleared by prep).
// C/D layout col=lane&31, reg->(r&3)+8*(r>>2)+4*(lane>>5); k-bijection symmetry
// and the 9th-MFMA nrm trick verified end-to-end rounds 3-11 (absmax 0).

#define NROWS 65536
#define DDIM 128
#define KCODES 1024
#define MARGIN1 0.30f    // s-space; hi-bf16 sigma ~0.05

typedef __attribute__((ext_vector_type(8))) short short8;
typedef __attribute__((ext_vector_type(16))) float f32x16;

__device__ inline ushort f2bf(float f) {            // RNE f32 -> bf16 bits
    union { float f; unsigned u; } v; v.f = f;
    unsigned r = v.u + 0x7fffu + ((v.u >> 16) & 1u);
    return (ushort)(r >> 16);
}
__device__ inline float bf2f(ushort b) {
    union { unsigned u; float f; } v; v.u = ((unsigned)b) << 16;
    return v.f;
}

__device__ inline void gload_lds16(const uint4* g, uint4* lds) {
    __builtin_amdgcn_global_load_lds((const __attribute__((address_space(1))) void*)g,
                                     (__attribute__((address_space(3))) void*)lds,
                                     16, 0, 0);
}

// ---------- fused prep: transpose + norms + e-hi pack + nrm hi/lo + x-hi pack ----------
// grid 4096 x 256.
__global__ void k_prep(const float* __restrict__ x, const float* __restrict__ e,
                       float* __restrict__ et, float* __restrict__ nrm,
                       double* __restrict__ nrm64, uint4* __restrict__ epq,
                       unsigned* __restrict__ nhl, uint4* __restrict__ xp,
                       int* __restrict__ wlc) {
    const int gid = blockIdx.x * blockDim.x + threadIdx.x;

    if (gid == 0) { wlc[0] = 0; wlc[1] = 0; }

    // x-hi fragment pack (all threads): xp[rt*512 + c*64 + lane]
    {
        int lane = gid & 63, c = (gid >> 6) & 7, rt = gid >> 9;     // rt 0..2047
        int row = rt * 32 + (lane & 31);
        int kbase = c * 16 + ((lane >> 5) << 3);
        const float4* xr4 = reinterpret_cast<const float4*>(x + (size_t)row * DDIM + kbase);
        float4 u = xr4[0], v = xr4[1];
        float fv[8] = {u.x, u.y, u.z, u.w, v.x, v.y, v.z, v.w};
        union { ushort s[8]; uint4 q; } pk;
        #pragma unroll
        for (int j = 0; j < 8; ++j) pk.s[j] = f2bf(fv[j]);
        xp[gid] = pk.q;
    }

    // transpose (first 131072): et[k][d] = e[d][k]
    if (gid < 131072) {
        int d = gid >> 10, k = gid & 1023;
        et[k * DDIM + d] = e[gid];
    }

    // e-hi fragment pack (first 16384): epq[nt*512 + c*64 + lane]
    if (gid < 16384) {
        int lane = gid & 63, c = (gid >> 6) & 7, nt = gid >> 9;
        int col = nt * 32 + (lane & 31);
        int kbase = c * 16 + ((lane >> 5) << 3);
        union { ushort s[8]; uint4 q; } pk;
        #pragma unroll
        for (int j = 0; j < 8; ++j)
            pk.s[j] = f2bf(e[(kbase + j) * KCODES + col]);
        epq[(size_t)nt * 512 + c * 64 + lane] = pk.q;
    }

    // norms (threads 32768..40959): 8 lanes per code, shfl reduce
    if (gid >= 32768 && gid < 32768 + 8192) {
        int t2 = gid - 32768;
        int k = t2 >> 3, part = t2 & 7;
        double s = 0.0;
        #pragma unroll
        for (int j = 0; j < 16; ++j) {
            double v = (double)e[(part * 16 + j) * KCODES + k];
            s = fma(v, v, s);
        }
        #pragma unroll
        for (int m = 1; m < 8; m <<= 1) s += __shfl_xor(s, m);
        if (part == 0) {
            nrm64[k] = s; nrm[k] = (float)s;
            float t0 = (float)(-0.5 * s);
            ushort hb = f2bf(t0);
            ushort lb = f2bf(t0 - bf2f(hb));
            nhl[k] = (unsigned)hb | ((unsigned)lb << 16);
        }
    }
}

// ---------- phase 1: swapped-operand hi-bf16 MFMA argmin ----------
// grid 2048 = 256 rowgroups x 8 code-eighths. Block = 4 waves; each wave owns
// TWO rowtiles (interleaved MFMA chains). 32 KB LDS stage-once; barrier-free loop.
__global__ __launch_bounds__(256, 3) void k_argmin32(const uint4* __restrict__ xp,
                                                     const uint4* __restrict__ epq,
                                                     const unsigned* __restrict__ nhl,
                                                     unsigned* __restrict__ pb1,
                                                     float* __restrict__ pb2) {
    __shared__ uint4 sbuf[2048];      // 32 KB: 4 e-hi tiles
    __shared__ unsigned snhl[128];    // this eighth's -nrm/2 hi/lo

    const int tid = threadIdx.x;
    const int lane = tid & 63;
    const int w = tid >> 6;
    const int kq = blockIdx.x & 7;                 // code eighth
    const int rg = blockIdx.x >> 3;                // rowgroup (256 rows)
    const int rtA = rg * 8 + w * 2;                // this wave's rowtiles
    const int rtB = rtA + 1;
    const int lrow = lane & 31;
    const int lgrp = lane >> 5;

    // stage eighth: 4 tiles (8 x 16B per thread) + nhl slice
    #pragma unroll
    for (int i = 0; i < 8; ++i)
        gload_lds16(epq + (size_t)kq * 2048 + i * 256 + tid,
                    &sbuf[i * 256 + (w << 6)]);
    if (tid < 32)
        gload_lds16(reinterpret_cast<const uint4*>(nhl) + kq * 32 + tid,
                    reinterpret_cast<uint4*>(snhl));

    // x-hi fragments for both rowtiles (pre-packed, coalesced)
    short8 ahA[8], ahB[8];
    #pragma unroll
    for (int c = 0; c < 8; ++c) {
        union { uint4 q; short8 s; } ua, ub;
        ua.q = xp[(size_t)rtA * 512 + c * 64 + lane];
        ub.q = xp[(size_t)rtB * 512 + c * 64 + lane];
        ahA[c] = ua.s; ahB[c] = ub.s;
    }
    // 9th-MFMA B operand: ones at k=0,1
    short8 bx = {0, 0, 0, 0, 0, 0, 0, 0};
    if (lgrp == 0) { bx[0] = (short)0x3F80; bx[1] = (short)0x3F80; }

    int cidlow[16];
    #pragma unroll
    for (int r = 0; r < 16; ++r)
        cidlow[r] = (((r & 3) + ((r >> 2) << 3)) | (lgrp << 2));

    asm volatile("s_waitcnt vmcnt(0)" ::: "memory");
    __syncthreads();                  // staged; barrier-free main loop

    float kA1 = -3.4e38f, kA2 = -3.4e38f;
    float kB1 = -3.4e38f, kB2 = -3.4e38f;

    for (int t = 0; t < 4; ++t) {
        f32x16 aA, aB;
        #pragma unroll
        for (int r = 0; r < 16; ++r) { aA[r] = 0.f; aB[r] = 0.f; }

        #pragma unroll
        for (int c = 0; c < 8; ++c) {
            union { uint4 q; short8 s; } ef;
            ef.q = sbuf[t * 512 + c * 64 + lane];
            aA = __builtin_amdgcn_mfma_f32_32x32x16_bf16(ef.s, ahA[c], aA, 0, 0, 0);
            aB = __builtin_amdgcn_mfma_f32_32x32x16_bf16(ef.s, ahB[c], aB, 0, 0, 0);
        }
        unsigned hl = snhl[t * 32 + lrow];
        short8 ax = {0, 0, 0, 0, 0, 0, 0, 0};
        if (lgrp == 0) { ax[0] = (short)(hl & 0xFFFF); ax[1] = (short)(hl >> 16); }
        aA = __builtin_amdgcn_mfma_f32_32x32x16_bf16(ax, bx, aA, 0, 0, 0);
        aB = __builtin_amdgcn_mfma_f32_32x32x16_bf16(ax, bx, aB, 0, 0, 0);

        // 3 VALU per key: v_and_or pack, v_med3 (new 2nd-best), v_max (new best)
        #pragma unroll
        for (int r = 0; r < 16; ++r) {
            unsigned cid = (unsigned)((t << 5) | cidlow[r]);       // 0..127
            float keyA = __uint_as_float((__float_as_uint(aA[r]) & 0xFFFFFF00u) | cid);
            float keyB = __uint_as_float((__float_as_uint(aB[r]) & 0xFFFFFF00u) | cid);
            kA2 = __builtin_amdgcn_fmed3f(kA1, kA2, keyA);
            kA1 = fmaxf(kA1, keyA);
            kB2 = __builtin_amdgcn_fmed3f(kB1, kB2, keyB);
            kB1 = fmaxf(kB1, keyB);
        }
    }

    // combine the two 32-lane halves (sorted-pair merge via med3)
    {
        float o1 = __shfl_xor(kA1, 32);
        float o2 = __shfl_xor(kA2, 32);
        float m2 = __builtin_amdgcn_fmed3f(kA1, o1, fmaxf(kA2, o2));
        float m1 = fmaxf(kA1, o1);
        if (lane < 32) {
            size_t o = (size_t)(rtA * 32 + lrow) * 8 + kq;
            pb1[o] = __float_as_uint(m1);
            pb2[o] = m2;
        }
    }
    {
        float o1 = __shfl_xor(kB1, 32);
        float o2 = __shfl_xor(kB2, 32);
        float m2 = __builtin_amdgcn_fmed3f(kB1, o1, fmaxf(kB2, o2));
        float m1 = fmaxf(kB1, o1);
        if (lane < 32) {
            size_t o = (size_t)(rtB * 32 + lrow) * 8 + kq;
            pb1[o] = __float_as_uint(m1);
            pb2[o] = m2;
        }
    }
}

// ---------- merge 8 eighths per row (coalesced uint4/float4 loads) ----------
__global__ void k_merge(const unsigned* __restrict__ pb1, const float* __restrict__ pb2,
                        int* __restrict__ idx, int* __restrict__ wlc,
                        int* __restrict__ wl) {
    int r = blockIdx.x * blockDim.x + threadIdx.x;     // 0..NROWS-1
    const uint4*  p1 = reinterpret_cast<const uint4*>(pb1 + (size_t)r * 8);
    const float4* p2 = reinterpret_cast<const float4*>(pb2 + (size_t)r * 8);
    uint4 A = p1[0], B = p1[1];
    float4 C = p2[0], D = p2[1];
    unsigned K[8] = {A.x, A.y, A.z, A.w, B.x, B.y, B.z, B.w};
    float    S[8] = {C.x, C.y, C.z, C.w, D.x, D.y, D.z, D.w};

    float best = -3.4e38f, sec = -3.4e38f;
    unsigned ub = 0; int bq = 0;
    #pragma unroll
    for (int q = 0; q < 8; ++q) {
        float m  = __uint_as_float(K[q] & 0xFFFFFF00u);
        float s2 = __uint_as_float(__float_as_uint(S[q]) & 0xFFFFFF00u);
        bool t = m > best;
        sec = fmaxf(sec, fmaxf(s2, t ? best : m));
        ub = t ? K[q] : ub;
        bq = t ? q : bq;
        best = t ? m : best;
    }
    int code = bq * 128 + (int)(ub & 255u);            // local cid < 128
    idx[r] = code;
    if (2.f * (best - sec) < MARGIN1) {                // s-gap = 2*(m1-m2)
        int slot = atomicAdd(wlc, 1);
        wl[slot] = r;
    }
}

// ---------- rescan: EXACT f64 re-argmin, 8 rows/block share one e-sweep ----------
__global__ __launch_bounds__(256) void k_rescan(const float* __restrict__ x,
                                                const float* __restrict__ e,
                                                const double* __restrict__ nrm64,
                                                const int* __restrict__ wlc,
                                                const int* __restrict__ wl,
                                                int* __restrict__ idx) {
    __shared__ float  xs[8][DDIM];
    __shared__ double rb1[8][256];
    __shared__ int    ri[8][256];
    const int tid = threadIdx.x, lane = tid & 63, wv = tid >> 6;
    const int n = *wlc;

    for (int i0 = blockIdx.x * 8; i0 < n; i0 += gridDim.x * 8) {
        {                                   // 8 rows x 32 float4 = 256 threads
            int j = tid >> 5, d4 = tid & 31;
            int ii = i0 + j;
            int row = wl[ii < n ? ii : i0];
            *reinterpret_cast<float4*>(&xs[j][d4 * 4]) =
                *reinterpret_cast<const float4*>(&x[(size_t)row * DDIM + d4 * 4]);
        }
        __syncthreads();

        double acc[4][8];
        #pragma unroll
        for (int kk = 0; kk < 4; ++kk)
            #pragma unroll
            for (int j = 0; j < 8; ++j) acc[kk][j] = 0.0;

        for (int d = 0; d < DDIM; ++d) {
            double xv[8];
            #pragma unroll
            for (int j = 0; j < 8; ++j) xv[j] = (double)xs[j][d];
            #pragma unroll
            for (int kk = 0; kk < 4; ++kk) {
                double ev = (double)e[d * KCODES + kk * 256 + tid];        // coalesced
                #pragma unroll
                for (int j = 0; j < 8; ++j)
                    acc[kk][j] = fma(ev, xv[j], acc[kk][j]);
            }
        }

        #pragma unroll
        for (int j = 0; j < 8; ++j) {
            double b1 = 1e300; int bi = 0;
            #pragma unroll
            for (int kk = 0; kk < 4; ++kk) {
                int k = kk * 256 + tid;                 // ascending per thread
                double s = nrm64[k] - 2.0 * acc[kk][j];
                if (s < b1) { b1 = s; bi = k; }
            }
            rb1[j][tid] = b1; ri[j][tid] = bi;
        }
        __syncthreads();

        // wave wv reduces rows wv and wv+4 (first-min tiebreak)
        #pragma unroll
        for (int jj = 0; jj < 2; ++jj) {
            int j = wv + jj * 4;
            double b1 = 1e300; int bi = 0x7FFFFFFF;
            #pragma unroll
            for (int p = 0; p < 4; ++p) {
                int t2 = lane + p * 64;
                double o1 = rb1[j][t2]; int oi = ri[j][t2];
                bool take = (o1 < b1) || (o1 == b1 && oi < bi);
                b1 = take ? o1 : b1;
                bi = take ? oi : bi;
            }
            #pragma unroll
            for (int m = 1; m < 64; m <<= 1) {
                double o1 = __shfl_xor(b1, m);
                int    oi = __shfl_xor(bi, m);
                bool take = (o1 < b1) || (o1 == b1 && oi < bi);
                b1 = take ? o1 : b1;
                bi = take ? oi : bi;
            }
            if (lane == 0 && i0 + j < n)
                idx[wl[i0 + j]] = bi;
        }
        __syncthreads();
    }
}

// ---------- gather + f32 STE (overwrites ALL of d_out, incl. xp scratch) ----------
__global__ void k_gather(const float* __restrict__ x, const float* __restrict__ et,
                         const int* __restrict__ idxp, float* __restrict__ out) {
    int gid = blockIdx.x * blockDim.x + threadIdx.x;   // NROWS*32
    int row = gid >> 5, d4 = gid & 31;
    float4 q = reinterpret_cast<const float4*>(et)[(size_t)idxp[row] * 32 + d4];
    float4 xv = reinterpret_cast<const float4*>(x)[gid];
    float4 o;
    o.x = xv.x + (q.x - xv.x);
    o.y = xv.y + (q.y - xv.y);
    o.z = xv.z + (q.z - xv.z);
    o.w = xv.w + (q.w - xv.w);
    reinterpret_cast<float4*>(out)[gid] = o;
}

extern "C" void kernel_launch(void* const* d_in, const int* in_sizes, int n_in,
                              void* d_out, int out_size, void* d_ws, size_t ws_size,
                              hipStream_t stream) {
    const float* x = (const float*)d_in[0];
    const float* e = (const float*)d_in[1];
    float* out = (float*)d_out;

    // ws layout (f32 slot units; all segments 16B-aligned). ~5.6 MB.
    double*   nrm64 = (double*)d_ws;                     // 2048 slots
    float*    et    = (float*)d_ws + 2048;               // 131072
    float*    nrm   = et + 131072;                       // 1024
    int*      idx   = (int*)(nrm + 1024);                // 65536
    int*      wlc   = idx + NROWS;                       // 4
    int*      wl    = wlc + 4;                           // 65536
    uint4*    epq   = (uint4*)(wl + NROWS);              // 16384 uint4 (e hi)
    unsigned* nhl   = (unsigned*)(epq + 16384);          // 1024
    unsigned* pb1   = nhl + 1024;                        // 8*65536  [row][8]
    float*    pb2   = (float*)(pb1 + 8 * NROWS);         // 8*65536  [row][8]
    // x-hi fragment pack lives in d_out (16 MB < 32 MB); k_gather overwrites it.
    uint4*    xp    = (uint4*)d_out;

    k_prep<<<4096, 256, 0, stream>>>(x, e, et, nrm, nrm64, epq, nhl, xp, wlc);
    k_argmin32<<<2048, 256, 0, stream>>>(xp, epq, nhl, pb1, pb2);
    k_merge<<<NROWS / 256, 256, 0, stream>>>(pb1, pb2, idx, wlc, wl);
    k_rescan<<<512, 256, 0, stream>>>(x, e, nrm64, wlc, wl, idx);
    k_gather<<<(NROWS * 32) / 256, 256, 0, stream>>>(x, et, idx, out);
}

// Round 13
// 125.162 us; speedup vs baseline: 1.8096x; 1.8096x over previous
//
#include <hip/hip_runtime.h>

// VectorQuantizer: x (64,32,32,128) f32, embeddings (128,1024) f32.
// out = x + (q - x), q = e.T[argmin_k ||x_row - e_k||^2]
//
// Cascade (each stage only needs enough precision to RANK):
//   phase 1 (hi-bf16 MFMA, swapped operands A=codes/B=x-rows): per-row argmin
//     in-lane over packed keys (m = dot - nrm/2, 7-bit local code id in mantissa
//     LSBs); -nrm/2 folded in via 9th MFMA. Grid = 256 rowgroups x 8 eighths;
//     2 rowtiles per wave (interleaved MFMA chains). Top-2 via v_med3_f32.
//   merge: 8 eighths/row, pb layout [row][8] (uint4/float4 loads);
//     s-gap < MARGIN1=0.30 -> wl (~4% rows).
//   rescan: EXACT f64 re-argmin, 4 rows/block (r11-proven; acc[4][4]=32 VGPRs --
//     the r12 8-row variant spilled acc to scratch: VGPR=68, 135us. REVERTED).
// 5 dispatches (wlc cleared by prep).
// C/D layout col=lane&31, reg->(r&3)+8*(r>>2)+4*(lane>>5); k-bijection symmetry
// and the 9th-MFMA nrm trick verified end-to-end rounds 3-12 (absmax 0).

#define NROWS 65536
#define DDIM 128
#define KCODES 1024
#define MARGIN1 0.30f    // s-space; hi-bf16 sigma ~0.05

typedef __attribute__((ext_vector_type(8))) short short8;
typedef __attribute__((ext_vector_type(16))) float f32x16;

__device__ inline ushort f2bf(float f) {            // RNE f32 -> bf16 bits
    union { float f; unsigned u; } v; v.f = f;
    unsigned r = v.u + 0x7fffu + ((v.u >> 16) & 1u);
    return (ushort)(r >> 16);
}
__device__ inline float bf2f(ushort b) {
    union { unsigned u; float f; } v; v.u = ((unsigned)b) << 16;
    return v.f;
}

__device__ inline void gload_lds16(const uint4* g, uint4* lds) {
    __builtin_amdgcn_global_load_lds((const __attribute__((address_space(1))) void*)g,
                                     (__attribute__((address_space(3))) void*)lds,
                                     16, 0, 0);
}

// ---------- fused prep: transpose + norms + e-hi pack + nrm hi/lo + x-hi pack ----------
// grid 4096 x 256.
__global__ void k_prep(const float* __restrict__ x, const float* __restrict__ e,
                       float* __restrict__ et, float* __restrict__ nrm,
                       double* __restrict__ nrm64, uint4* __restrict__ epq,
                       unsigned* __restrict__ nhl, uint4* __restrict__ xp,
                       int* __restrict__ wlc) {
    const int gid = blockIdx.x * blockDim.x + threadIdx.x;

    if (gid == 0) { wlc[0] = 0; wlc[1] = 0; }

    // x-hi fragment pack (all threads): xp[rt*512 + c*64 + lane]
    {
        int lane = gid & 63, c = (gid >> 6) & 7, rt = gid >> 9;     // rt 0..2047
        int row = rt * 32 + (lane & 31);
        int kbase = c * 16 + ((lane >> 5) << 3);
        const float4* xr4 = reinterpret_cast<const float4*>(x + (size_t)row * DDIM + kbase);
        float4 u = xr4[0], v = xr4[1];
        float fv[8] = {u.x, u.y, u.z, u.w, v.x, v.y, v.z, v.w};
        union { ushort s[8]; uint4 q; } pk;
        #pragma unroll
        for (int j = 0; j < 8; ++j) pk.s[j] = f2bf(fv[j]);
        xp[gid] = pk.q;
    }

    // transpose (first 131072): et[k][d] = e[d][k]
    if (gid < 131072) {
        int d = gid >> 10, k = gid & 1023;
        et[k * DDIM + d] = e[gid];
    }

    // e-hi fragment pack (first 16384): epq[nt*512 + c*64 + lane]
    if (gid < 16384) {
        int lane = gid & 63, c = (gid >> 6) & 7, nt = gid >> 9;
        int col = nt * 32 + (lane & 31);
        int kbase = c * 16 + ((lane >> 5) << 3);
        union { ushort s[8]; uint4 q; } pk;
        #pragma unroll
        for (int j = 0; j < 8; ++j)
            pk.s[j] = f2bf(e[(kbase + j) * KCODES + col]);
        epq[(size_t)nt * 512 + c * 64 + lane] = pk.q;
    }

    // norms (threads 32768..40959): 8 lanes per code, shfl reduce
    if (gid >= 32768 && gid < 32768 + 8192) {
        int t2 = gid - 32768;
        int k = t2 >> 3, part = t2 & 7;
        double s = 0.0;
        #pragma unroll
        for (int j = 0; j < 16; ++j) {
            double v = (double)e[(part * 16 + j) * KCODES + k];
            s = fma(v, v, s);
        }
        #pragma unroll
        for (int m = 1; m < 8; m <<= 1) s += __shfl_xor(s, m);
        if (part == 0) {
            nrm64[k] = s; nrm[k] = (float)s;
            float t0 = (float)(-0.5 * s);
            ushort hb = f2bf(t0);
            ushort lb = f2bf(t0 - bf2f(hb));
            nhl[k] = (unsigned)hb | ((unsigned)lb << 16);
        }
    }
}

// ---------- phase 1: swapped-operand hi-bf16 MFMA argmin ----------
// grid 2048 = 256 rowgroups x 8 code-eighths. Block = 4 waves; each wave owns
// TWO rowtiles (interleaved MFMA chains). 32 KB LDS stage-once; barrier-free loop.
__global__ __launch_bounds__(256, 3) void k_argmin32(const uint4* __restrict__ xp,
                                                     const uint4* __restrict__ epq,
                                                     const unsigned* __restrict__ nhl,
                                                     unsigned* __restrict__ pb1,
                                                     float* __restrict__ pb2) {
    __shared__ uint4 sbuf[2048];      // 32 KB: 4 e-hi tiles
    __shared__ unsigned snhl[128];    // this eighth's -nrm/2 hi/lo

    const int tid = threadIdx.x;
    const int lane = tid & 63;
    const int w = tid >> 6;
    const int kq = blockIdx.x & 7;                 // code eighth
    const int rg = blockIdx.x >> 3;                // rowgroup (256 rows)
    const int rtA = rg * 8 + w * 2;                // this wave's rowtiles
    const int rtB = rtA + 1;
    const int lrow = lane & 31;
    const int lgrp = lane >> 5;

    // stage eighth: 4 tiles (8 x 16B per thread) + nhl slice
    #pragma unroll
    for (int i = 0; i < 8; ++i)
        gload_lds16(epq + (size_t)kq * 2048 + i * 256 + tid,
                    &sbuf[i * 256 + (w << 6)]);
    if (tid < 32)
        gload_lds16(reinterpret_cast<const uint4*>(nhl) + kq * 32 + tid,
                    reinterpret_cast<uint4*>(snhl));

    // x-hi fragments for both rowtiles (pre-packed, coalesced)
    short8 ahA[8], ahB[8];
    #pragma unroll
    for (int c = 0; c < 8; ++c) {
        union { uint4 q; short8 s; } ua, ub;
        ua.q = xp[(size_t)rtA * 512 + c * 64 + lane];
        ub.q = xp[(size_t)rtB * 512 + c * 64 + lane];
        ahA[c] = ua.s; ahB[c] = ub.s;
    }
    // 9th-MFMA B operand: ones at k=0,1
    short8 bx = {0, 0, 0, 0, 0, 0, 0, 0};
    if (lgrp == 0) { bx[0] = (short)0x3F80; bx[1] = (short)0x3F80; }

    int cidlow[16];
    #pragma unroll
    for (int r = 0; r < 16; ++r)
        cidlow[r] = (((r & 3) + ((r >> 2) << 3)) | (lgrp << 2));

    asm volatile("s_waitcnt vmcnt(0)" ::: "memory");
    __syncthreads();                  // staged; barrier-free main loop

    float kA1 = -3.4e38f, kA2 = -3.4e38f;
    float kB1 = -3.4e38f, kB2 = -3.4e38f;

    for (int t = 0; t < 4; ++t) {
        f32x16 aA, aB;
        #pragma unroll
        for (int r = 0; r < 16; ++r) { aA[r] = 0.f; aB[r] = 0.f; }

        #pragma unroll
        for (int c = 0; c < 8; ++c) {
            union { uint4 q; short8 s; } ef;
            ef.q = sbuf[t * 512 + c * 64 + lane];
            aA = __builtin_amdgcn_mfma_f32_32x32x16_bf16(ef.s, ahA[c], aA, 0, 0, 0);
            aB = __builtin_amdgcn_mfma_f32_32x32x16_bf16(ef.s, ahB[c], aB, 0, 0, 0);
        }
        unsigned hl = snhl[t * 32 + lrow];
        short8 ax = {0, 0, 0, 0, 0, 0, 0, 0};
        if (lgrp == 0) { ax[0] = (short)(hl & 0xFFFF); ax[1] = (short)(hl >> 16); }
        aA = __builtin_amdgcn_mfma_f32_32x32x16_bf16(ax, bx, aA, 0, 0, 0);
        aB = __builtin_amdgcn_mfma_f32_32x32x16_bf16(ax, bx, aB, 0, 0, 0);

        // 3 VALU per key: v_and_or pack, v_med3 (new 2nd-best), v_max (new best)
        #pragma unroll
        for (int r = 0; r < 16; ++r) {
            unsigned cid = (unsigned)((t << 5) | cidlow[r]);       // 0..127
            float keyA = __uint_as_float((__float_as_uint(aA[r]) & 0xFFFFFF00u) | cid);
            float keyB = __uint_as_float((__float_as_uint(aB[r]) & 0xFFFFFF00u) | cid);
            kA2 = __builtin_amdgcn_fmed3f(kA1, kA2, keyA);
            kA1 = fmaxf(kA1, keyA);
            kB2 = __builtin_amdgcn_fmed3f(kB1, kB2, keyB);
            kB1 = fmaxf(kB1, keyB);
        }
    }

    // combine the two 32-lane halves (sorted-pair merge via med3)
    {
        float o1 = __shfl_xor(kA1, 32);
        float o2 = __shfl_xor(kA2, 32);
        float m2 = __builtin_amdgcn_fmed3f(kA1, o1, fmaxf(kA2, o2));
        float m1 = fmaxf(kA1, o1);
        if (lane < 32) {
            size_t o = (size_t)(rtA * 32 + lrow) * 8 + kq;
            pb1[o] = __float_as_uint(m1);
            pb2[o] = m2;
        }
    }
    {
        float o1 = __shfl_xor(kB1, 32);
        float o2 = __shfl_xor(kB2, 32);
        float m2 = __builtin_amdgcn_fmed3f(kB1, o1, fmaxf(kB2, o2));
        float m1 = fmaxf(kB1, o1);
        if (lane < 32) {
            size_t o = (size_t)(rtB * 32 + lrow) * 8 + kq;
            pb1[o] = __float_as_uint(m1);
            pb2[o] = m2;
        }
    }
}

// ---------- merge 8 eighths per row (coalesced uint4/float4 loads) ----------
__global__ void k_merge(const unsigned* __restrict__ pb1, const float* __restrict__ pb2,
                        int* __restrict__ idx, int* __restrict__ wlc,
                        int* __restrict__ wl) {
    int r = blockIdx.x * blockDim.x + threadIdx.x;     // 0..NROWS-1
    const uint4*  p1 = reinterpret_cast<const uint4*>(pb1 + (size_t)r * 8);
    const float4* p2 = reinterpret_cast<const float4*>(pb2 + (size_t)r * 8);
    uint4 A = p1[0], B = p1[1];
    float4 C = p2[0], D = p2[1];
    unsigned K[8] = {A.x, A.y, A.z, A.w, B.x, B.y, B.z, B.w};
    float    S[8] = {C.x, C.y, C.z, C.w, D.x, D.y, D.z, D.w};

    float best = -3.4e38f, sec = -3.4e38f;
    unsigned ub = 0; int bq = 0;
    #pragma unroll
    for (int q = 0; q < 8; ++q) {
        float m  = __uint_as_float(K[q] & 0xFFFFFF00u);
        float s2 = __uint_as_float(__float_as_uint(S[q]) & 0xFFFFFF00u);
        bool t = m > best;
        sec = fmaxf(sec, fmaxf(s2, t ? best : m));
        ub = t ? K[q] : ub;
        bq = t ? q : bq;
        best = t ? m : best;
    }
    int code = bq * 128 + (int)(ub & 255u);            // local cid < 128
    idx[r] = code;
    if (2.f * (best - sec) < MARGIN1) {                // s-gap = 2*(m1-m2)
        int slot = atomicAdd(wlc, 1);
        wl[slot] = r;
    }
}

// ---------- rescan: EXACT f64 re-argmin, 4 rows/block (r11-proven) ----------
__global__ __launch_bounds__(256) void k_rescan(const float* __restrict__ x,
                                                const float* __restrict__ e,
                                                const double* __restrict__ nrm64,
                                                const int* __restrict__ wlc,
                                                const int* __restrict__ wl,
                                                int* __restrict__ idx) {
    __shared__ float  xs[4][DDIM];
    __shared__ double rb1[4][256];
    __shared__ int    ri[4][256];
    const int tid = threadIdx.x, lane = tid & 63, wv = tid >> 6;
    const int n = *wlc;

    for (int i0 = blockIdx.x * 4; i0 < n; i0 += gridDim.x * 4) {
        if (tid < 128) {                   // 4 rows x 32 float4
            int j = tid >> 5, d4 = tid & 31;
            int ii = i0 + j;
            int row = wl[ii < n ? ii : i0];
            *reinterpret_cast<float4*>(&xs[j][d4 * 4]) =
                *reinterpret_cast<const float4*>(&x[(size_t)row * DDIM + d4 * 4]);
        }
        __syncthreads();

        double acc[4][4];
        #pragma unroll
        for (int kk = 0; kk < 4; ++kk)
            #pragma unroll
            for (int j = 0; j < 4; ++j) acc[kk][j] = 0.0;

        for (int d = 0; d < DDIM; d += 2) {
            double xv0[4], xv1[4];
            #pragma unroll
            for (int j = 0; j < 4; ++j) {
                xv0[j] = (double)xs[j][d];
                xv1[j] = (double)xs[j][d + 1];
            }
            #pragma unroll
            for (int kk = 0; kk < 4; ++kk) {
                double ev0 = (double)e[d * KCODES + kk * 256 + tid];       // coalesced
                double ev1 = (double)e[(d + 1) * KCODES + kk * 256 + tid];
                #pragma unroll
                for (int j = 0; j < 4; ++j) {
                    acc[kk][j] = fma(ev0, xv0[j], acc[kk][j]);
                    acc[kk][j] = fma(ev1, xv1[j], acc[kk][j]);
                }
            }
        }

        #pragma unroll
        for (int j = 0; j < 4; ++j) {
            double b1 = 1e300; int bi = 0;
            #pragma unroll
            for (int kk = 0; kk < 4; ++kk) {
                int k = kk * 256 + tid;                 // ascending per thread
                double s = nrm64[k] - 2.0 * acc[kk][j];
                if (s < b1) { b1 = s; bi = k; }
            }
            rb1[j][tid] = b1; ri[j][tid] = bi;
        }
        __syncthreads();

        // wave wv reduces row wv over 256 thread-entries (first-min tiebreak)
        {
            double b1 = 1e300; int bi = 0x7FFFFFFF;
            #pragma unroll
            for (int p = 0; p < 4; ++p) {
                int t2 = lane + p * 64;
                double o1 = rb1[wv][t2]; int oi = ri[wv][t2];
                bool take = (o1 < b1) || (o1 == b1 && oi < bi);
                b1 = take ? o1 : b1;
                bi = take ? oi : bi;
            }
            #pragma unroll
            for (int m = 1; m < 64; m <<= 1) {
                double o1 = __shfl_xor(b1, m);
                int    oi = __shfl_xor(bi, m);
                bool take = (o1 < b1) || (o1 == b1 && oi < bi);
                b1 = take ? o1 : b1;
                bi = take ? oi : bi;
            }
            if (lane == 0 && i0 + wv < n)
                idx[wl[i0 + wv]] = bi;
        }
        __syncthreads();
    }
}

// ---------- gather + f32 STE (overwrites ALL of d_out, incl. xp scratch) ----------
__global__ void k_gather(const float* __restrict__ x, const float* __restrict__ et,
                         const int* __restrict__ idxp, float* __restrict__ out) {
    int gid = blockIdx.x * blockDim.x + threadIdx.x;   // NROWS*32
    int row = gid >> 5, d4 = gid & 31;
    float4 q = reinterpret_cast<const float4*>(et)[(size_t)idxp[row] * 32 + d4];
    float4 xv = reinterpret_cast<const float4*>(x)[gid];
    float4 o;
    o.x = xv.x + (q.x - xv.x);
    o.y = xv.y + (q.y - xv.y);
    o.z = xv.z + (q.z - xv.z);
    o.w = xv.w + (q.w - xv.w);
    reinterpret_cast<float4*>(out)[gid] = o;
}

extern "C" void kernel_launch(void* const* d_in, const int* in_sizes, int n_in,
                              void* d_out, int out_size, void* d_ws, size_t ws_size,
                              hipStream_t stream) {
    const float* x = (const float*)d_in[0];
    const float* e = (const float*)d_in[1];
    float* out = (float*)d_out;

    // ws layout (f32 slot units; all segments 16B-aligned). ~5.6 MB.
    double*   nrm64 = (double*)d_ws;                     // 2048 slots
    float*    et    = (float*)d_ws + 2048;               // 131072
    float*    nrm   = et + 131072;                       // 1024
    int*      idx   = (int*)(nrm + 1024);                // 65536
    int*      wlc   = idx + NROWS;                       // 4
    int*      wl    = wlc + 4;                           // 65536
    uint4*    epq   = (uint4*)(wl + NROWS);              // 16384 uint4 (e hi)
    unsigned* nhl   = (unsigned*)(epq + 16384);          // 1024
    unsigned* pb1   = nhl + 1024;                        // 8*65536  [row][8]
    float*    pb2   = (float*)(pb1 + 8 * NROWS);         // 8*65536  [row][8]
    // x-hi fragment pack lives in d_out (16 MB < 32 MB); k_gather overwrites it.
    uint4*    xp    = (uint4*)d_out;

    k_prep<<<4096, 256, 0, stream>>>(x, e, et, nrm, nrm64, epq, nhl, xp, wlc);
    k_argmin32<<<2048, 256, 0, stream>>>(xp, epq, nhl, pb1, pb2);
    k_merge<<<NROWS / 256, 256, 0, stream>>>(pb1, pb2, idx, wlc, wl);
    k_rescan<<<1024, 256, 0, stream>>>(x, e, nrm64, wlc, wl, idx);
    k_gather<<<(NROWS * 32) / 256, 256, 0, stream>>>(x, et, idx, out);
}

// Round 14
// 94.153 us; speedup vs baseline: 2.4055x; 1.3293x over previous
//
#include <hip/hip_runtime.h>

// VectorQuantizer: x (64,32,32,128) f32, embeddings (128,1024) f32.
// out = x + (q - x), q = e.T[argmin_k ||x_row - e_k||^2]
//
// Cascade (each stage only needs enough precision to RANK):
//   phase 1 (hi-bf16 MFMA, swapped operands A=codes/B=x-rows): per-row argmin
//     in-lane over packed keys (m = dot - nrm/2, 8-bit local code id in mantissa
//     LSBs); -nrm/2 folded in via 9th MFMA. Grid = 256 rowgroups x 4 QUARTERS
//     (Q=4 halves xp re-read vs Q=8); 2 rowtiles per wave (interleaved chains).
//     Top-2 via v_med3_f32. pb layout [q][row]: coalesced 128B wave writes.
//   merge: 4 quarters/row (4 coalesced loads); gap < MARGIN1 -> wl (~4% rows).
//   rescan: EXACT f64 re-argmin, 4 rows/block (r11-proven; 8-row variant spilled).
// REGISTER DISCIPLINE (r13 post-mortem): (256,3) capped the unified VGPR+AGPR
// file at ~170 -> 84 arch VGPRs -> 110 MB scratch WRITE/dispatch. (256,2) is the
// r7-proven no-spill config. cidlow[] array removed (16 regs -> inline).
// C/D layout col=lane&31, reg->(r&3)+8*(r>>2)+4*(lane>>5); k-bijection symmetry
// and the 9th-MFMA nrm trick verified end-to-end rounds 3-13 (absmax 0).

#define NROWS 65536
#define DDIM 128
#define KCODES 1024
#define MARGIN1 0.30f    // s-space; hi-bf16 sigma ~0.05, cid noise ~0.016

typedef __attribute__((ext_vector_type(8))) short short8;
typedef __attribute__((ext_vector_type(16))) float f32x16;

__device__ inline ushort f2bf(float f) {            // RNE f32 -> bf16 bits
    union { float f; unsigned u; } v; v.f = f;
    unsigned r = v.u + 0x7fffu + ((v.u >> 16) & 1u);
    return (ushort)(r >> 16);
}
__device__ inline float bf2f(ushort b) {
    union { unsigned u; float f; } v; v.u = ((unsigned)b) << 16;
    return v.f;
}

__device__ inline void gload_lds16(const uint4* g, uint4* lds) {
    __builtin_amdgcn_global_load_lds((const __attribute__((address_space(1))) void*)g,
                                     (__attribute__((address_space(3))) void*)lds,
                                     16, 0, 0);
}

// ---------- fused prep: transpose + norms + e-hi pack + nrm hi/lo + x-hi pack ----------
// grid 4096 x 256.
__global__ void k_prep(const float* __restrict__ x, const float* __restrict__ e,
                       float* __restrict__ et, float* __restrict__ nrm,
                       double* __restrict__ nrm64, uint4* __restrict__ epq,
                       unsigned* __restrict__ nhl, uint4* __restrict__ xp,
                       int* __restrict__ wlc) {
    const int gid = blockIdx.x * blockDim.x + threadIdx.x;

    if (gid == 0) { wlc[0] = 0; wlc[1] = 0; }

    // x-hi fragment pack (all threads): xp[rt*512 + c*64 + lane]
    {
        int lane = gid & 63, c = (gid >> 6) & 7, rt = gid >> 9;     // rt 0..2047
        int row = rt * 32 + (lane & 31);
        int kbase = c * 16 + ((lane >> 5) << 3);
        const float4* xr4 = reinterpret_cast<const float4*>(x + (size_t)row * DDIM + kbase);
        float4 u = xr4[0], v = xr4[1];
        float fv[8] = {u.x, u.y, u.z, u.w, v.x, v.y, v.z, v.w};
        union { ushort s[8]; uint4 q; } pk;
        #pragma unroll
        for (int j = 0; j < 8; ++j) pk.s[j] = f2bf(fv[j]);
        xp[gid] = pk.q;
    }

    // transpose (first 131072): et[k][d] = e[d][k]
    if (gid < 131072) {
        int d = gid >> 10, k = gid & 1023;
        et[k * DDIM + d] = e[gid];
    }

    // e-hi fragment pack (first 16384): epq[nt*512 + c*64 + lane]
    if (gid < 16384) {
        int lane = gid & 63, c = (gid >> 6) & 7, nt = gid >> 9;
        int col = nt * 32 + (lane & 31);
        int kbase = c * 16 + ((lane >> 5) << 3);
        union { ushort s[8]; uint4 q; } pk;
        #pragma unroll
        for (int j = 0; j < 8; ++j)
            pk.s[j] = f2bf(e[(kbase + j) * KCODES + col]);
        epq[(size_t)nt * 512 + c * 64 + lane] = pk.q;
    }

    // norms (threads 32768..40959): 8 lanes per code, shfl reduce
    if (gid >= 32768 && gid < 32768 + 8192) {
        int t2 = gid - 32768;
        int k = t2 >> 3, part = t2 & 7;
        double s = 0.0;
        #pragma unroll
        for (int j = 0; j < 16; ++j) {
            double v = (double)e[(part * 16 + j) * KCODES + k];
            s = fma(v, v, s);
        }
        #pragma unroll
        for (int m = 1; m < 8; m <<= 1) s += __shfl_xor(s, m);
        if (part == 0) {
            nrm64[k] = s; nrm[k] = (float)s;
            float t0 = (float)(-0.5 * s);
            ushort hb = f2bf(t0);
            ushort lb = f2bf(t0 - bf2f(hb));
            nhl[k] = (unsigned)hb | ((unsigned)lb << 16);
        }
    }
}

// ---------- phase 1: swapped-operand hi-bf16 MFMA argmin, quarter-split ----------
// grid 1024 = 256 rowgroups x 4 quarters. Block = 4 waves; each wave owns TWO
// rowtiles (interleaved MFMA chains). 65.5 KB LDS stage-once; barrier-free loop.
__global__ __launch_bounds__(256, 2) void k_argmin32(const uint4* __restrict__ xp,
                                                     const uint4* __restrict__ epq,
                                                     const unsigned* __restrict__ nhl,
                                                     unsigned* __restrict__ pb1,
                                                     float* __restrict__ pb2) {
    __shared__ uint4 sbuf[4096];      // 64 KB: 8 e-hi tiles (256 codes)
    __shared__ unsigned snhl[256];    // 1 KB: this quarter's -nrm/2 hi/lo

    const int tid = threadIdx.x;
    const int lane = tid & 63;
    const int w = tid >> 6;
    const int kq = blockIdx.x & 3;                 // code quarter
    const int rg = blockIdx.x >> 2;                // rowgroup (256 rows)
    const int rtA = rg * 8 + w * 2;                // this wave's rowtiles
    const int rtB = rtA + 1;
    const int lrow = lane & 31;
    const int lgrp = lane >> 5;

    // stage quarter: 8 tiles (16 x 16B per thread) + nhl slice (wave 0)
    #pragma unroll
    for (int i = 0; i < 16; ++i)
        gload_lds16(epq + (size_t)kq * 4096 + i * 256 + tid,
                    &sbuf[i * 256 + (w << 6)]);
    if (tid < 64)
        gload_lds16(reinterpret_cast<const uint4*>(nhl) + kq * 64 + tid,
                    reinterpret_cast<uint4*>(snhl));

    // x-hi fragments for both rowtiles (pre-packed, coalesced)
    short8 ahA[8], ahB[8];
    #pragma unroll
    for (int c = 0; c < 8; ++c) {
        union { uint4 q; short8 s; } ua, ub;
        ua.q = xp[(size_t)rtA * 512 + c * 64 + lane];
        ub.q = xp[(size_t)rtB * 512 + c * 64 + lane];
        ahA[c] = ua.s; ahB[c] = ub.s;
    }
    // 9th-MFMA B operand: ones at k=0,1
    short8 bx = {0, 0, 0, 0, 0, 0, 0, 0};
    if (lgrp == 0) { bx[0] = (short)0x3F80; bx[1] = (short)0x3F80; }
    const unsigned cid4 = (unsigned)(lgrp << 2);   // the only runtime cid bit

    asm volatile("s_waitcnt vmcnt(0)" ::: "memory");
    __syncthreads();                  // staged; barrier-free main loop

    float kA1 = -3.4e38f, kA2 = -3.4e38f;
    float kB1 = -3.4e38f, kB2 = -3.4e38f;

    for (int t = 0; t < 8; ++t) {
        f32x16 aA, aB;
        #pragma unroll
        for (int r = 0; r < 16; ++r) { aA[r] = 0.f; aB[r] = 0.f; }

        #pragma unroll
        for (int c = 0; c < 8; ++c) {
            union { uint4 q; short8 s; } ef;
            ef.q = sbuf[t * 512 + c * 64 + lane];
            aA = __builtin_amdgcn_mfma_f32_32x32x16_bf16(ef.s, ahA[c], aA, 0, 0, 0);
            aB = __builtin_amdgcn_mfma_f32_32x32x16_bf16(ef.s, ahB[c], aB, 0, 0, 0);
        }
        unsigned hl = snhl[t * 32 + lrow];
        short8 ax = {0, 0, 0, 0, 0, 0, 0, 0};
        if (lgrp == 0) { ax[0] = (short)(hl & 0xFFFF); ax[1] = (short)(hl >> 16); }
        aA = __builtin_amdgcn_mfma_f32_32x32x16_bf16(ax, bx, aA, 0, 0, 0);
        aB = __builtin_amdgcn_mfma_f32_32x32x16_bf16(ax, bx, aB, 0, 0, 0);

        // 3 VALU per key: v_and_or pack, v_med3 (new 2nd-best), v_max (new best)
        #pragma unroll
        for (int r = 0; r < 16; ++r) {
            unsigned cid = (unsigned)((t << 5) | ((r & 3) + ((r >> 2) << 3))) | cid4;
            float keyA = __uint_as_float((__float_as_uint(aA[r]) & 0xFFFFFF00u) | cid);
            float keyB = __uint_as_float((__float_as_uint(aB[r]) & 0xFFFFFF00u) | cid);
            kA2 = __builtin_amdgcn_fmed3f(kA1, kA2, keyA);
            kA1 = fmaxf(kA1, keyA);
            kB2 = __builtin_amdgcn_fmed3f(kB1, kB2, keyB);
            kB1 = fmaxf(kB1, keyB);
        }
    }

    // combine the two 32-lane halves (sorted-pair merge via med3)
    {
        float o1 = __shfl_xor(kA1, 32);
        float o2 = __shfl_xor(kA2, 32);
        float m2 = __builtin_amdgcn_fmed3f(kA1, o1, fmaxf(kA2, o2));
        float m1 = fmaxf(kA1, o1);
        if (lane < 32) {                           // coalesced 128B wave-half write
            size_t o = (size_t)kq * NROWS + rtA * 32 + lrow;
            pb1[o] = __float_as_uint(m1);
            pb2[o] = m2;
        }
    }
    {
        float o1 = __shfl_xor(kB1, 32);
        float o2 = __shfl_xor(kB2, 32);
        float m2 = __builtin_amdgcn_fmed3f(kB1, o1, fmaxf(kB2, o2));
        float m1 = fmaxf(kB1, o1);
        if (lane < 32) {
            size_t o = (size_t)kq * NROWS + rtB * 32 + lrow;
            pb1[o] = __float_as_uint(m1);
            pb2[o] = m2;
        }
    }
}

// ---------- merge 4 quarters per row ([q][row]: coalesced per-q loads) ----------
__global__ void k_merge(const unsigned* __restrict__ pb1, const float* __restrict__ pb2,
                        int* __restrict__ idx, int* __restrict__ wlc,
                        int* __restrict__ wl) {
    int r = blockIdx.x * blockDim.x + threadIdx.x;     // 0..NROWS-1
    float best = -3.4e38f, sec = -3.4e38f;
    unsigned ub = 0; int bq = 0;
    #pragma unroll
    for (int q = 0; q < 4; ++q) {
        unsigned k1 = pb1[(size_t)q * NROWS + r];
        float    s2 = __uint_as_float(__float_as_uint(pb2[(size_t)q * NROWS + r]) & 0xFFFFFF00u);
        float    m  = __uint_as_float(k1 & 0xFFFFFF00u);
        bool t = m > best;
        sec = fmaxf(sec, fmaxf(s2, t ? best : m));
        ub = t ? k1 : ub;
        bq = t ? q : bq;
        best = t ? m : best;
    }
    int code = bq * 256 + (int)(ub & 255u);            // local cid < 256
    idx[r] = code;
    if (2.f * (best - sec) < MARGIN1) {                // s-gap = 2*(m1-m2)
        int slot = atomicAdd(wlc, 1);
        wl[slot] = r;
    }
}

// ---------- rescan: EXACT f64 re-argmin, 4 rows/block (r11-proven) ----------
__global__ __launch_bounds__(256) void k_rescan(const float* __restrict__ x,
                                                const float* __restrict__ e,
                                                const double* __restrict__ nrm64,
                                                const int* __restrict__ wlc,
                                                const int* __restrict__ wl,
                                                int* __restrict__ idx) {
    __shared__ float  xs[4][DDIM];
    __shared__ double rb1[4][256];
    __shared__ int    ri[4][256];
    const int tid = threadIdx.x, lane = tid & 63, wv = tid >> 6;
    const int n = *wlc;

    for (int i0 = blockIdx.x * 4; i0 < n; i0 += gridDim.x * 4) {
        if (tid < 128) {                   // 4 rows x 32 float4
            int j = tid >> 5, d4 = tid & 31;
            int ii = i0 + j;
            int row = wl[ii < n ? ii : i0];
            *reinterpret_cast<float4*>(&xs[j][d4 * 4]) =
                *reinterpret_cast<const float4*>(&x[(size_t)row * DDIM + d4 * 4]);
        }
        __syncthreads();

        double acc[4][4];
        #pragma unroll
        for (int kk = 0; kk < 4; ++kk)
            #pragma unroll
            for (int j = 0; j < 4; ++j) acc[kk][j] = 0.0;

        for (int d = 0; d < DDIM; d += 2) {
            double xv0[4], xv1[4];
            #pragma unroll
            for (int j = 0; j < 4; ++j) {
                xv0[j] = (double)xs[j][d];
                xv1[j] = (double)xs[j][d + 1];
            }
            #pragma unroll
            for (int kk = 0; kk < 4; ++kk) {
                double ev0 = (double)e[d * KCODES + kk * 256 + tid];       // coalesced
                double ev1 = (double)e[(d + 1) * KCODES + kk * 256 + tid];
                #pragma unroll
                for (int j = 0; j < 4; ++j) {
                    acc[kk][j] = fma(ev0, xv0[j], acc[kk][j]);
                    acc[kk][j] = fma(ev1, xv1[j], acc[kk][j]);
                }
            }
        }

        #pragma unroll
        for (int j = 0; j < 4; ++j) {
            double b1 = 1e300; int bi = 0;
            #pragma unroll
            for (int kk = 0; kk < 4; ++kk) {
                int k = kk * 256 + tid;                 // ascending per thread
                double s = nrm64[k] - 2.0 * acc[kk][j];
                if (s < b1) { b1 = s; bi = k; }
            }
            rb1[j][tid] = b1; ri[j][tid] = bi;
        }
        __syncthreads();

        // wave wv reduces row wv over 256 thread-entries (first-min tiebreak)
        {
            double b1 = 1e300; int bi = 0x7FFFFFFF;
            #pragma unroll
            for (int p = 0; p < 4; ++p) {
                int t2 = lane + p * 64;
                double o1 = rb1[wv][t2]; int oi = ri[wv][t2];
                bool take = (o1 < b1) || (o1 == b1 && oi < bi);
                b1 = take ? o1 : b1;
                bi = take ? oi : bi;
            }
            #pragma unroll
            for (int m = 1; m < 64; m <<= 1) {
                double o1 = __shfl_xor(b1, m);
                int    oi = __shfl_xor(bi, m);
                bool take = (o1 < b1) || (o1 == b1 && oi < bi);
                b1 = take ? o1 : b1;
                bi = take ? oi : bi;
            }
            if (lane == 0 && i0 + wv < n)
                idx[wl[i0 + wv]] = bi;
        }
        __syncthreads();
    }
}

// ---------- gather + f32 STE (overwrites ALL of d_out, incl. xp scratch) ----------
__global__ void k_gather(const float* __restrict__ x, const float* __restrict__ et,
                         const int* __restrict__ idxp, float* __restrict__ out) {
    int gid = blockIdx.x * blockDim.x + threadIdx.x;   // NROWS*32
    int row = gid >> 5, d4 = gid & 31;
    float4 q = reinterpret_cast<const float4*>(et)[(size_t)idxp[row] * 32 + d4];
    float4 xv = reinterpret_cast<const float4*>(x)[gid];
    float4 o;
    o.x = xv.x + (q.x - xv.x);
    o.y = xv.y + (q.y - xv.y);
    o.z = xv.z + (q.z - xv.z);
    o.w = xv.w + (q.w - xv.w);
    reinterpret_cast<float4*>(out)[gid] = o;
}

extern "C" void kernel_launch(void* const* d_in, const int* in_sizes, int n_in,
                              void* d_out, int out_size, void* d_ws, size_t ws_size,
                              hipStream_t stream) {
    const float* x = (const float*)d_in[0];
    const float* e = (const float*)d_in[1];
    float* out = (float*)d_out;

    // ws layout (f32 slot units; all segments 16B-aligned). ~4.3 MB.
    double*   nrm64 = (double*)d_ws;                     // 2048 slots
    float*    et    = (float*)d_ws + 2048;               // 131072
    float*    nrm   = et + 131072;                       // 1024
    int*      idx   = (int*)(nrm + 1024);                // 65536
    int*      wlc   = idx + NROWS;                       // 4
    int*      wl    = wlc + 4;                           // 65536
    uint4*    epq   = (uint4*)(wl + NROWS);              // 16384 uint4 (e hi)
    unsigned* nhl   = (unsigned*)(epq + 16384);          // 1024
    unsigned* pb1   = nhl + 1024;                        // 4*65536  [q][row]
    float*    pb2   = (float*)(pb1 + 4 * NROWS);         // 4*65536  [q][row]
    // x-hi fragment pack lives in d_out (16 MB < 32 MB); k_gather overwrites it.
    uint4*    xp    = (uint4*)d_out;

    k_prep<<<4096, 256, 0, stream>>>(x, e, et, nrm, nrm64, epq, nhl, xp, wlc);
    k_argmin32<<<1024, 256, 0, stream>>>(xp, epq, nhl, pb1, pb2);
    k_merge<<<NROWS / 256, 256, 0, stream>>>(pb1, pb2, idx, wlc, wl);
    k_rescan<<<1024, 256, 0, stream>>>(x, e, nrm64, wlc, wl, idx);
    k_gather<<<(NROWS * 32) / 256, 256, 0, stream>>>(x, et, idx, out);
}

// Round 15
// 91.696 us; speedup vs baseline: 2.4700x; 1.0268x over previous
//
#include <hip/hip_runtime.h>

// VectorQuantizer: x (64,32,32,128) f32, embeddings (128,1024) f32.
// out = x + (q - x), q = e.T[argmin_k ||x_row - e_k||^2]
//
// Cascade (each stage only needs enough precision to RANK):
//   phase 1 (hi-bf16 MFMA, swapped operands A=codes/B=x-rows): per-row argmin
//     in-lane over packed keys (m = dot - nrm/2, 8-bit local code id in mantissa
//     LSBs); -nrm/2 folded in via 9th MFMA. Grid = 256 rowgroups x 4 quarters;
//     2 rowtiles per wave (interleaved chains); top-2 via v_med3_f32;
//     pb layout [q][row] (coalesced 128B wave-half writes). (256,2): no spill.
//   k_finish (merge+gather FUSED): merge 4 quarters/row -> code; STE-gather the
//     row's output immediately; gap < MARGIN1 -> worklist (provisional output).
//   k_rescan: EXACT f64 re-argmin of flagged rows (4 rows/block, r11-proven),
//     writes the corrected OUTPUT rows directly (no idx round-trip).
// 4 dispatches (wlc cleared by prep).
// C/D layout col=lane&31, reg->(r&3)+8*(r>>2)+4*(lane>>5); k-bijection symmetry
// and the 9th-MFMA nrm trick verified end-to-end rounds 3-14 (absmax 0).

#define NROWS 65536
#define DDIM 128
#define KCODES 1024
#define MARGIN1 0.30f    // s-space; hi-bf16 sigma ~0.05, cid noise ~0.016

typedef __attribute__((ext_vector_type(8))) short short8;
typedef __attribute__((ext_vector_type(16))) float f32x16;

__device__ inline ushort f2bf(float f) {            // RNE f32 -> bf16 bits
    union { float f; unsigned u; } v; v.f = f;
    unsigned r = v.u + 0x7fffu + ((v.u >> 16) & 1u);
    return (ushort)(r >> 16);
}
__device__ inline float bf2f(ushort b) {
    union { unsigned u; float f; } v; v.u = ((unsigned)b) << 16;
    return v.f;
}

__device__ inline void gload_lds16(const uint4* g, uint4* lds) {
    __builtin_amdgcn_global_load_lds((const __attribute__((address_space(1))) void*)g,
                                     (__attribute__((address_space(3))) void*)lds,
                                     16, 0, 0);
}

// ---------- fused prep: transpose + norms + e-hi pack + nrm hi/lo + x-hi pack ----------
// grid 4096 x 256.
__global__ void k_prep(const float* __restrict__ x, const float* __restrict__ e,
                       float* __restrict__ et, float* __restrict__ nrm,
                       double* __restrict__ nrm64, uint4* __restrict__ epq,
                       unsigned* __restrict__ nhl, uint4* __restrict__ xp,
                       int* __restrict__ wlc) {
    const int gid = blockIdx.x * blockDim.x + threadIdx.x;

    if (gid == 0) { wlc[0] = 0; wlc[1] = 0; }

    // x-hi fragment pack (all threads): xp[rt*512 + c*64 + lane]
    {
        int lane = gid & 63, c = (gid >> 6) & 7, rt = gid >> 9;     // rt 0..2047
        int row = rt * 32 + (lane & 31);
        int kbase = c * 16 + ((lane >> 5) << 3);
        const float4* xr4 = reinterpret_cast<const float4*>(x + (size_t)row * DDIM + kbase);
        float4 u = xr4[0], v = xr4[1];
        float fv[8] = {u.x, u.y, u.z, u.w, v.x, v.y, v.z, v.w};
        union { ushort s[8]; uint4 q; } pk;
        #pragma unroll
        for (int j = 0; j < 8; ++j) pk.s[j] = f2bf(fv[j]);
        xp[gid] = pk.q;
    }

    // transpose (first 131072): et[k][d] = e[d][k]
    if (gid < 131072) {
        int d = gid >> 10, k = gid & 1023;
        et[k * DDIM + d] = e[gid];
    }

    // e-hi fragment pack (first 16384): epq[nt*512 + c*64 + lane]
    if (gid < 16384) {
        int lane = gid & 63, c = (gid >> 6) & 7, nt = gid >> 9;
        int col = nt * 32 + (lane & 31);
        int kbase = c * 16 + ((lane >> 5) << 3);
        union { ushort s[8]; uint4 q; } pk;
        #pragma unroll
        for (int j = 0; j < 8; ++j)
            pk.s[j] = f2bf(e[(kbase + j) * KCODES + col]);
        epq[(size_t)nt * 512 + c * 64 + lane] = pk.q;
    }

    // norms (threads 32768..40959): 8 lanes per code, shfl reduce
    if (gid >= 32768 && gid < 32768 + 8192) {
        int t2 = gid - 32768;
        int k = t2 >> 3, part = t2 & 7;
        double s = 0.0;
        #pragma unroll
        for (int j = 0; j < 16; ++j) {
            double v = (double)e[(part * 16 + j) * KCODES + k];
            s = fma(v, v, s);
        }
        #pragma unroll
        for (int m = 1; m < 8; m <<= 1) s += __shfl_xor(s, m);
        if (part == 0) {
            nrm64[k] = s; nrm[k] = (float)s;
            float t0 = (float)(-0.5 * s);
            ushort hb = f2bf(t0);
            ushort lb = f2bf(t0 - bf2f(hb));
            nhl[k] = (unsigned)hb | ((unsigned)lb << 16);
        }
    }
}

// ---------- phase 1: swapped-operand hi-bf16 MFMA argmin, quarter-split ----------
// grid 1024 = 256 rowgroups x 4 quarters. Block = 4 waves; each wave owns TWO
// rowtiles (interleaved MFMA chains). 65.5 KB LDS stage-once; barrier-free loop.
__global__ __launch_bounds__(256, 2) void k_argmin32(const uint4* __restrict__ xp,
                                                     const uint4* __restrict__ epq,
                                                     const unsigned* __restrict__ nhl,
                                                     unsigned* __restrict__ pb1,
                                                     float* __restrict__ pb2) {
    __shared__ uint4 sbuf[4096];      // 64 KB: 8 e-hi tiles (256 codes)
    __shared__ unsigned snhl[256];    // 1 KB: this quarter's -nrm/2 hi/lo

    const int tid = threadIdx.x;
    const int lane = tid & 63;
    const int w = tid >> 6;
    const int kq = blockIdx.x & 3;                 // code quarter
    const int rg = blockIdx.x >> 2;                // rowgroup (256 rows)
    const int rtA = rg * 8 + w * 2;                // this wave's rowtiles
    const int rtB = rtA + 1;
    const int lrow = lane & 31;
    const int lgrp = lane >> 5;

    // stage quarter: 8 tiles (16 x 16B per thread) + nhl slice (wave 0)
    #pragma unroll
    for (int i = 0; i < 16; ++i)
        gload_lds16(epq + (size_t)kq * 4096 + i * 256 + tid,
                    &sbuf[i * 256 + (w << 6)]);
    if (tid < 64)
        gload_lds16(reinterpret_cast<const uint4*>(nhl) + kq * 64 + tid,
                    reinterpret_cast<uint4*>(snhl));

    // x-hi fragments for both rowtiles (pre-packed, coalesced)
    short8 ahA[8], ahB[8];
    #pragma unroll
    for (int c = 0; c < 8; ++c) {
        union { uint4 q; short8 s; } ua, ub;
        ua.q = xp[(size_t)rtA * 512 + c * 64 + lane];
        ub.q = xp[(size_t)rtB * 512 + c * 64 + lane];
        ahA[c] = ua.s; ahB[c] = ub.s;
    }
    // 9th-MFMA B operand: ones at k=0,1
    short8 bx = {0, 0, 0, 0, 0, 0, 0, 0};
    if (lgrp == 0) { bx[0] = (short)0x3F80; bx[1] = (short)0x3F80; }
    const unsigned cid4 = (unsigned)(lgrp << 2);   // the only runtime cid bit

    asm volatile("s_waitcnt vmcnt(0)" ::: "memory");
    __syncthreads();                  // staged; barrier-free main loop

    float kA1 = -3.4e38f, kA2 = -3.4e38f;
    float kB1 = -3.4e38f, kB2 = -3.4e38f;

    for (int t = 0; t < 8; ++t) {
        f32x16 aA, aB;
        #pragma unroll
        for (int r = 0; r < 16; ++r) { aA[r] = 0.f; aB[r] = 0.f; }

        #pragma unroll
        for (int c = 0; c < 8; ++c) {
            union { uint4 q; short8 s; } ef;
            ef.q = sbuf[t * 512 + c * 64 + lane];
            aA = __builtin_amdgcn_mfma_f32_32x32x16_bf16(ef.s, ahA[c], aA, 0, 0, 0);
            aB = __builtin_amdgcn_mfma_f32_32x32x16_bf16(ef.s, ahB[c], aB, 0, 0, 0);
        }
        unsigned hl = snhl[t * 32 + lrow];
        short8 ax = {0, 0, 0, 0, 0, 0, 0, 0};
        if (lgrp == 0) { ax[0] = (short)(hl & 0xFFFF); ax[1] = (short)(hl >> 16); }
        aA = __builtin_amdgcn_mfma_f32_32x32x16_bf16(ax, bx, aA, 0, 0, 0);
        aB = __builtin_amdgcn_mfma_f32_32x32x16_bf16(ax, bx, aB, 0, 0, 0);

        // 3 VALU per key: v_and_or pack, v_med3 (new 2nd-best), v_max (new best)
        #pragma unroll
        for (int r = 0; r < 16; ++r) {
            unsigned cid = (unsigned)((t << 5) | ((r & 3) + ((r >> 2) << 3))) | cid4;
            float keyA = __uint_as_float((__float_as_uint(aA[r]) & 0xFFFFFF00u) | cid);
            float keyB = __uint_as_float((__float_as_uint(aB[r]) & 0xFFFFFF00u) | cid);
            kA2 = __builtin_amdgcn_fmed3f(kA1, kA2, keyA);
            kA1 = fmaxf(kA1, keyA);
            kB2 = __builtin_amdgcn_fmed3f(kB1, kB2, keyB);
            kB1 = fmaxf(kB1, keyB);
        }
    }

    // combine the two 32-lane halves (sorted-pair merge via med3)
    {
        float o1 = __shfl_xor(kA1, 32);
        float o2 = __shfl_xor(kA2, 32);
        float m2 = __builtin_amdgcn_fmed3f(kA1, o1, fmaxf(kA2, o2));
        float m1 = fmaxf(kA1, o1);
        if (lane < 32) {                           // coalesced 128B wave-half write
            size_t o = (size_t)kq * NROWS + rtA * 32 + lrow;
            pb1[o] = __float_as_uint(m1);
            pb2[o] = m2;
        }
    }
    {
        float o1 = __shfl_xor(kB1, 32);
        float o2 = __shfl_xor(kB2, 32);
        float m2 = __builtin_amdgcn_fmed3f(kB1, o1, fmaxf(kB2, o2));
        float m1 = fmaxf(kB1, o1);
        if (lane < 32) {
            size_t o = (size_t)kq * NROWS + rtB * 32 + lrow;
            pb1[o] = __float_as_uint(m1);
            pb2[o] = m2;
        }
    }
}

// ---------- k_finish: merge 4 quarters + STE-gather, fused ----------
// grid 256 x 256: block owns 256 rows. Phase A: per-thread merge -> code in LDS,
// flagged rows -> worklist. Phase B: block streams 256 rows x 32 float4 out.
__global__ __launch_bounds__(256) void k_finish(const float* __restrict__ x,
                                                const float* __restrict__ et,
                                                const unsigned* __restrict__ pb1,
                                                const float* __restrict__ pb2,
                                                int* __restrict__ wlc,
                                                int* __restrict__ wl,
                                                float* __restrict__ out) {
    __shared__ int scode[256];
    const int tid = threadIdx.x;
    const int base = blockIdx.x * 256;
    const int r = base + tid;

    // merge ([q][row] layout: coalesced per-q loads)
    float best = -3.4e38f, sec = -3.4e38f;
    unsigned ub = 0; int bq = 0;
    #pragma unroll
    for (int q = 0; q < 4; ++q) {
        unsigned k1 = pb1[(size_t)q * NROWS + r];
        float    s2 = __uint_as_float(__float_as_uint(pb2[(size_t)q * NROWS + r]) & 0xFFFFFF00u);
        float    m  = __uint_as_float(k1 & 0xFFFFFF00u);
        bool t = m > best;
        sec = fmaxf(sec, fmaxf(s2, t ? best : m));
        ub = t ? k1 : ub;
        bq = t ? q : bq;
        best = t ? m : best;
    }
    scode[tid] = bq * 256 + (int)(ub & 255u);
    if (2.f * (best - sec) < MARGIN1) {                // s-gap = 2*(m1-m2)
        int slot = atomicAdd(wlc, 1);
        wl[slot] = r;
    }
    __syncthreads();

    // STE-gather: 256 rows x 32 float4 = 8192 float4, 32 per thread
    const float4* x4  = reinterpret_cast<const float4*>(x);
    const float4* et4 = reinterpret_cast<const float4*>(et);
    float4* o4 = reinterpret_cast<float4*>(out);
    #pragma unroll
    for (int i = 0; i < 32; ++i) {
        int j = i * 256 + tid;                         // 0..8191
        int rl = j >> 5, d4 = j & 31;
        size_t g = (size_t)(base + rl) * 32 + d4;
        float4 q = et4[(size_t)scode[rl] * 32 + d4];
        float4 xv = x4[g];
        float4 o;
        o.x = xv.x + (q.x - xv.x);
        o.y = xv.y + (q.y - xv.y);
        o.z = xv.z + (q.z - xv.z);
        o.w = xv.w + (q.w - xv.w);
        o4[g] = o;
    }
}

// ---------- rescan: EXACT f64 re-argmin + direct output write ----------
// 4 rows/block (r11-proven register budget: acc[4][4] f64).
__global__ __launch_bounds__(256) void k_rescan(const float* __restrict__ x,
                                                const float* __restrict__ e,
                                                const float* __restrict__ et,
                                                const double* __restrict__ nrm64,
                                                const int* __restrict__ wlc,
                                                const int* __restrict__ wl,
                                                float* __restrict__ out) {
    __shared__ float  xs[4][DDIM];
    __shared__ double rb1[4][256];
    __shared__ int    ri[4][256];
    const int tid = threadIdx.x, lane = tid & 63, wv = tid >> 6;
    const int n = *wlc;

    for (int i0 = blockIdx.x * 4; i0 < n; i0 += gridDim.x * 4) {
        if (tid < 128) {                   // 4 rows x 32 float4
            int j = tid >> 5, d4 = tid & 31;
            int ii = i0 + j;
            int row = wl[ii < n ? ii : i0];
            *reinterpret_cast<float4*>(&xs[j][d4 * 4]) =
                *reinterpret_cast<const float4*>(&x[(size_t)row * DDIM + d4 * 4]);
        }
        __syncthreads();

        double acc[4][4];
        #pragma unroll
        for (int kk = 0; kk < 4; ++kk)
            #pragma unroll
            for (int j = 0; j < 4; ++j) acc[kk][j] = 0.0;

        for (int d = 0; d < DDIM; d += 2) {
            double xv0[4], xv1[4];
            #pragma unroll
            for (int j = 0; j < 4; ++j) {
                xv0[j] = (double)xs[j][d];
                xv1[j] = (double)xs[j][d + 1];
            }
            #pragma unroll
            for (int kk = 0; kk < 4; ++kk) {
                double ev0 = (double)e[d * KCODES + kk * 256 + tid];       // coalesced
                double ev1 = (double)e[(d + 1) * KCODES + kk * 256 + tid];
                #pragma unroll
                for (int j = 0; j < 4; ++j) {
                    acc[kk][j] = fma(ev0, xv0[j], acc[kk][j]);
                    acc[kk][j] = fma(ev1, xv1[j], acc[kk][j]);
                }
            }
        }

        #pragma unroll
        for (int j = 0; j < 4; ++j) {
            double b1 = 1e300; int bi = 0;
            #pragma unroll
            for (int kk = 0; kk < 4; ++kk) {
                int k = kk * 256 + tid;                 // ascending per thread
                double s = nrm64[k] - 2.0 * acc[kk][j];
                if (s < b1) { b1 = s; bi = k; }
            }
            rb1[j][tid] = b1; ri[j][tid] = bi;
        }
        __syncthreads();

        // wave wv reduces row wv (first-min tiebreak), then writes the output row
        {
            double b1 = 1e300; int bi = 0x7FFFFFFF;
            #pragma unroll
            for (int p = 0; p < 4; ++p) {
                int t2 = lane + p * 64;
                double o1 = rb1[wv][t2]; int oi = ri[wv][t2];
                bool take = (o1 < b1) || (o1 == b1 && oi < bi);
                b1 = take ? o1 : b1;
                bi = take ? oi : bi;
            }
            #pragma unroll
            for (int m = 1; m < 64; m <<= 1) {
                double o1 = __shfl_xor(b1, m);
                int    oi = __shfl_xor(bi, m);
                bool take = (o1 < b1) || (o1 == b1 && oi < bi);
                b1 = take ? o1 : b1;
                bi = take ? oi : bi;
            }
            if (i0 + wv < n && lane < 32) {            // all lanes hold bi now
                int row = wl[i0 + wv];
                float4 q = reinterpret_cast<const float4*>(et)[(size_t)bi * 32 + lane];
                float4 xv = *reinterpret_cast<const float4*>(&xs[wv][lane * 4]);
                float4 o;
                o.x = xv.x + (q.x - xv.x);
                o.y = xv.y + (q.y - xv.y);
                o.z = xv.z + (q.z - xv.z);
                o.w = xv.w + (q.w - xv.w);
                reinterpret_cast<float4*>(out)[(size_t)row * 32 + lane] = o;
            }
        }
        __syncthreads();
    }
}

extern "C" void kernel_launch(void* const* d_in, const int* in_sizes, int n_in,
                              void* d_out, int out_size, void* d_ws, size_t ws_size,
                              hipStream_t stream) {
    const float* x = (const float*)d_in[0];
    const float* e = (const float*)d_in[1];
    float* out = (float*)d_out;

    // ws layout (f32 slot units; all segments 16B-aligned). ~4.3 MB.
    double*   nrm64 = (double*)d_ws;                     // 2048 slots
    float*    et    = (float*)d_ws + 2048;               // 131072
    float*    nrm   = et + 131072;                       // 1024
    int*      wlc   = (int*)(nrm + 1024);                // 4
    int*      wl    = wlc + 4;                           // 65536
    uint4*    epq   = (uint4*)(wl + NROWS);              // 16384 uint4 (e hi)
    unsigned* nhl   = (unsigned*)(epq + 16384);          // 1024
    unsigned* pb1   = nhl + 1024;                        // 4*65536  [q][row]
    float*    pb2   = (float*)(pb1 + 4 * NROWS);         // 4*65536  [q][row]
    // x-hi fragment pack lives in d_out (16 MB < 32 MB); k_finish overwrites it.
    uint4*    xp    = (uint4*)d_out;

    k_prep<<<4096, 256, 0, stream>>>(x, e, et, nrm, nrm64, epq, nhl, xp, wlc);
    k_argmin32<<<1024, 256, 0, stream>>>(xp, epq, nhl, pb1, pb2);
    k_finish<<<NROWS / 256, 256, 0, stream>>>(x, et, pb1, pb2, wlc, wl, out);
    k_rescan<<<1024, 256, 0, stream>>>(x, e, et, nrm64, wlc, wl, out);
}